// Round 16
// baseline (285.126 us; speedup 1.0000x reference)
//
#include <hip/hip_runtime.h>
#include <math.h>

#define W 128
#define H 128
#define HW 16384
#define CIN 96
#define COUT 96
#define BATCH 16
#define NPIX (BATCH * HW)
#define BPITCH 104                 // padded B row pitch (bf16): 2-way banks max
#define BTAP (COUT * BPITCH)       // 9984 elems per tap image
#define BSTG 12288                 // LDS B elems (24576 B; 8 waves x 3 x 512)
#define NOT (27 * 32 * 32)         // wOT elems

typedef __bf16 bf16x8 __attribute__((ext_vector_type(8)));
typedef float f32x4 __attribute__((ext_vector_type(4)));
typedef unsigned int u32x4 __attribute__((ext_vector_type(4)));

typedef const unsigned int __attribute__((address_space(1))) gu32;
typedef unsigned int __attribute__((address_space(3))) lu32;
#define GLDS16(g, l) __builtin_amdgcn_global_load_lds((gu32*)(g), (lu32*)(l), 16, 0, 0)

__device__ inline float bflo(unsigned d) { union { unsigned u; float f; } t; t.u = d << 16; return t.f; }
__device__ inline float bfhi(unsigned d) { union { unsigned u; float f; } t; t.u = d & 0xffff0000u; return t.f; }

// ---------------------------------------------------------------------------
// Weight prep (R10-validated). Extra zero slack after the 9 tap images covers
// the 8-wave staging overshoot (waves 6-7 stage past 9984 into the slack).
// ---------------------------------------------------------------------------
__global__ void prep_weights(const float* __restrict__ weight,
                             const float* __restrict__ offset_w,
                             const float* __restrict__ mask_w,
                             __bf16* __restrict__ wOT,
                             __bf16* __restrict__ wBTp) {
  int idx = blockIdx.x * blockDim.x + threadIdx.x;
  if (idx < NOT) {
    int c = idx & 31;
    int o = (idx >> 5) & 31;
    int ks = idx >> 10;
    int tap = ks / 3;
    int cg = (ks % 3) * 32 + c;
    float v = 0.f;
    if (o < 18)      v = offset_w[(o * CIN + cg) * 9 + tap];
    else if (o < 27) v = mask_w[((o - 18) * CIN + cg) * 9 + tap];
    wOT[idx] = (__bf16)v;
  } else {
    int j = idx - NOT;
    if (j < 9 * BTAP + 2560) {     // +2560 zero slack for staging overshoot
      int c = j % BPITCH;
      int o = (j / BPITCH) % COUT;
      int tap = j / BTAP;
      float v = 0.f;
      if (tap < 9 && c < CIN) v = weight[(o * CIN + c) * 9 + tap];
      wBTp[j] = (__bf16)v;
    }
  }
}

// ---------------------------------------------------------------------------
// NHWC relayout (validated).
// ---------------------------------------------------------------------------
__global__ __launch_bounds__(256) void nhwc_kernel(const float* __restrict__ x,
                                                   __bf16* __restrict__ xT) {
  int tid = blockIdx.x * 256 + threadIdx.x;
  int b = tid >> 14, pix = tid & (HW - 1);
  const float* xp = x + (size_t)b * CIN * HW + pix;
  __bf16* op = xT + (size_t)tid * CIN;
#pragma unroll
  for (int c0 = 0; c0 < CIN; c0 += 8) {
    bf16x8 v;
#pragma unroll
    for (int j = 0; j < 8; ++j) v[j] = (__bf16)xp[(size_t)(c0 + j) * HW];
    *(bf16x8*)(op + c0) = v;
  }
}

// ---------------------------------------------------------------------------
// Kernel A v2 (R10-validated, unchanged): offset/mask conv as bf16 MFMA GEMM.
// ---------------------------------------------------------------------------
#define OISS_TAP(TAP, G) {                                                    \
    int ki = (TAP) / 3, kj = (TAP) % 3;                                       \
    int yy = h + ki - 1, xx = wg + kj - 1;                                    \
    bool ok = ((unsigned)yy < (unsigned)H) && ((unsigned)xx < (unsigned)W);   \
    unsigned vo = ok ? (unsigned)((yy * W + xx) * 192) + choff : 0x7f000000u; \
    asm volatile("buffer_load_dwordx4 %0, %1, %2, %3 offen"                   \
                 : "=v"(G[0]) : "v"(vo), "s"(rsrcX), "s"(0));                 \
    asm volatile("buffer_load_dwordx4 %0, %1, %2, %3 offen"                   \
                 : "=v"(G[1]) : "v"(vo), "s"(rsrcX), "s"(64));                \
    asm volatile("buffer_load_dwordx4 %0, %1, %2, %3 offen"                   \
                 : "=v"(G[2]) : "v"(vo), "s"(rsrcX), "s"(128));               \
  }

#define OISS_B(TAP)                                                           \
  _Pragma("unroll") for (int s = 0; s < 3; ++s)                               \
  _Pragma("unroll") for (int nt = 0; nt < 2; ++nt)                            \
    asm volatile("buffer_load_dwordx4 %0, %1, %2, %3 offen"                   \
                 : "=v"(bb[s * 2 + nt])                                       \
                 : "v"(voffB), "s"(rsrcW),                                    \
                   "s"((TAP) * 6144 + s * 2048 + nt * 1024));

#define OCOMP(GC)                                                             \
  _Pragma("unroll") for (int s = 0; s < 3; ++s) {                             \
    bf16x8 a = __builtin_bit_cast(bf16x8, GC[s]);                             \
    acc[0] = __builtin_amdgcn_mfma_f32_16x16x32_bf16(                         \
        a, __builtin_bit_cast(bf16x8, bb[s * 2 + 0]), acc[0], 0, 0, 0);       \
    acc[1] = __builtin_amdgcn_mfma_f32_16x16x32_bf16(                         \
        a, __builtin_bit_cast(bf16x8, bb[s * 2 + 1]), acc[1], 0, 0, 0);       \
  }

__global__ __launch_bounds__(256) void offmask_mfma(
    const __bf16* __restrict__ xT, const __bf16* __restrict__ wOT,
    const float* __restrict__ offset_b, const float* __restrict__ mask_b,
    float* __restrict__ offm) {
  int t = threadIdx.x;
  int lane = t & 63;
  int wv = __builtin_amdgcn_readfirstlane(t >> 6);
  int ln15 = lane & 15;

  int bid = (int)blockIdx.x;
  int nb = (bid & 7) * 512 + (bid >> 3);
  int b = nb >> 8;
  int rem = nb & 255;
  int h = rem >> 1;
  int w0 = (rem & 1) << 6;

  int pl = (wv << 4) + ln15;
  int wg = w0 + pl;
  unsigned choff = (unsigned)((lane >> 4) << 4);

  const __bf16* xb = xT + (size_t)b * HW * CIN;

  unsigned long long ba = (unsigned long long)(const void*)xb;
  u32x4 rsrcX;
  rsrcX.x = (unsigned)ba; rsrcX.y = (unsigned)(ba >> 32);
  rsrcX.z = (unsigned)(HW * 192);
  rsrcX.w = 0x00020000u;
  unsigned long long bwo = (unsigned long long)(const void*)wOT;
  u32x4 rsrcW;
  rsrcW.x = (unsigned)bwo; rsrcW.y = (unsigned)(bwo >> 32);
  rsrcW.z = (unsigned)(NOT * 2);
  rsrcW.w = 0x00020000u;
  unsigned voffB = (unsigned)(ln15 * 64 + ((lane >> 4) << 4));

  f32x4 acc[2];
  acc[0] = (f32x4){0.f, 0.f, 0.f, 0.f};
  acc[1] = (f32x4){0.f, 0.f, 0.f, 0.f};

  u32x4 gA[3], gB[3], bb[6];

  OISS_TAP(0, gA);
#pragma unroll
  for (int tap = 0; tap < 9; ++tap) {
    OISS_B(tap);
    if (tap < 8) {
      if (tap & 1) { OISS_TAP(tap + 1, gA); } else { OISS_TAP(tap + 1, gB); }
      asm volatile("s_waitcnt vmcnt(3)" ::: "memory");
    } else {
      asm volatile("s_waitcnt vmcnt(0)" ::: "memory");
    }
    __builtin_amdgcn_sched_barrier(0);
    if (tap & 1) { OCOMP(gB); } else { OCOMP(gA); }
  }

  float* ob = offm + (size_t)b * 27 * HW + (size_t)h * W;
  int prow = w0 + (wv << 4) + ((lane >> 4) << 2);
  {
    float bv = offset_b[ln15];
    float4 o4;
    o4.x = acc[0][0] + bv; o4.y = acc[0][1] + bv;
    o4.z = acc[0][2] + bv; o4.w = acc[0][3] + bv;
    *(float4*)(ob + (size_t)ln15 * HW + prow) = o4;
  }
  if (ln15 < 11) {
    int o = 16 + ln15;
    bool sig = (o >= 18);
    float bv = sig ? mask_b[o - 18] : offset_b[o];
    float4 o4;
    float v0 = acc[1][0] + bv, v1 = acc[1][1] + bv;
    float v2 = acc[1][2] + bv, v3 = acc[1][3] + bv;
    if (sig) {
      v0 = 1.f / (1.f + expf(-v0)); v1 = 1.f / (1.f + expf(-v1));
      v2 = 1.f / (1.f + expf(-v2)); v3 = 1.f / (1.f + expf(-v3));
    }
    o4.x = v0; o4.y = v1; o4.z = v2; o4.w = v3;
    *(float4*)(ob + (size_t)o * HW + prow) = o4;
  }
}

// ---------------------------------------------------------------------------
// Kernel B v15 = R15 structure at 512 threads / 8 waves per block.
// Occupancy lever: 4 blocks x 8 waves = 32 waves/CU (the hardware cap) vs
// 20 before. Per-wave code identical; block covers a full 128-pixel row;
// per-wave DMA 5->3 instrs (vmcnt(3)); barriers per pixel halve.
// __launch_bounds__(512,2): allocator unconstrained (natural VGPR 56;
// 8 waves/SIMD requires <=64 -- met naturally, degrades gracefully if not).
// ---------------------------------------------------------------------------
#define GISS(K, G, WD) {                                                      \
    float dyv = (float)offt[2 * (K)][pl];                                     \
    float dxv = (float)offt[2 * (K) + 1][pl];                                 \
    float mv  = (float)offt[18 + (K)][pl];                                    \
    int ki = (K) / 3, kj = (K) % 3;                                           \
    float py = (float)(h - 1 + ki) + dyv;                                     \
    float px = (float)(wg - 1 + kj) + dxv;                                    \
    float fy = floorf(py), fx = floorf(px);                                   \
    float wyf = py - fy, wxf = px - fx;                                       \
    int iy0 = (int)fy, ix0 = (int)fx;                                         \
    int iy1 = iy0 + 1, ix1 = ix0 + 1;                                         \
    bool y0ok = (unsigned)iy0 < (unsigned)H;                                  \
    bool y1ok = (unsigned)iy1 < (unsigned)H;                                  \
    bool x0ok = (unsigned)ix0 < (unsigned)W;                                  \
    bool x1ok = (unsigned)ix1 < (unsigned)W;                                  \
    WD[0] = (y0ok && x0ok) ? (1.f - wyf) * (1.f - wxf) * mv : 0.f;            \
    WD[1] = (y0ok && x1ok) ? (1.f - wyf) * wxf * mv : 0.f;                    \
    WD[2] = (y1ok && x0ok) ? wyf * (1.f - wxf) * mv : 0.f;                    \
    WD[3] = (y1ok && x1ok) ? wyf * wxf * mv : 0.f;                            \
    int cy0 = min(max(iy0, 0), H - 1), cy1 = min(max(iy1, 0), H - 1);         \
    int cx0 = min(max(ix0, 0), W - 1), cx1 = min(max(ix1, 0), W - 1);         \
    unsigned v00 = (unsigned)((cy0 * W + cx0) * 192) + choff;                 \
    unsigned v01 = (unsigned)((cy0 * W + cx1) * 192) + choff;                 \
    unsigned v10 = (unsigned)((cy1 * W + cx0) * 192) + choff;                 \
    unsigned v11 = (unsigned)((cy1 * W + cx1) * 192) + choff;                 \
    _Pragma("unroll") for (int ks = 0; ks < 3; ++ks) {                        \
      asm volatile("buffer_load_dwordx4 %0, %1, %2, %3 offen"                 \
                   : "=v"(G[ks * 4 + 0]) : "v"(v00), "s"(rsrcX), "s"(ks * 64)); \
      asm volatile("buffer_load_dwordx4 %0, %1, %2, %3 offen"                 \
                   : "=v"(G[ks * 4 + 1]) : "v"(v01), "s"(rsrcX), "s"(ks * 64)); \
      asm volatile("buffer_load_dwordx4 %0, %1, %2, %3 offen"                 \
                   : "=v"(G[ks * 4 + 2]) : "v"(v10), "s"(rsrcX), "s"(ks * 64)); \
      asm volatile("buffer_load_dwordx4 %0, %1, %2, %3 offen"                 \
                   : "=v"(G[ks * 4 + 3]) : "v"(v11), "s"(rsrcX), "s"(ks * 64)); \
    } }

#define COMBINE_KS(G, KS, WV, AF)                                             \
  _Pragma("unroll") for (int j = 0; j < 8; ++j) {                             \
    unsigned d00 = G[(KS) * 4 + 0][j >> 1], d01 = G[(KS) * 4 + 1][j >> 1];    \
    unsigned d10 = G[(KS) * 4 + 2][j >> 1], d11 = G[(KS) * 4 + 3][j >> 1];    \
    float v00 = (j & 1) ? bfhi(d00) : bflo(d00);                              \
    float v01 = (j & 1) ? bfhi(d01) : bflo(d01);                              \
    float v10 = (j & 1) ? bfhi(d10) : bflo(d10);                              \
    float v11 = (j & 1) ? bfhi(d11) : bflo(d11);                              \
    AF[j] = (__bf16)(WV[0] * v00 + WV[1] * v01 + WV[2] * v10 + WV[3] * v11);  \
  }

// 8 waves x 3 x 512-elem DMA = 12288 elems staged (tap image = 9984; excess
// lands in Blds slack, never read; global overshoot covered by wBTp zero pad)
#define STAGE_B(K) {                                                          \
    const __bf16* src = wBTp + (size_t)(K) * BTAP + (size_t)wv * 1536 +       \
                        (size_t)lane * 8;                                     \
    __bf16* dst = Blds + wv * 1536;                                           \
    _Pragma("unroll") for (int q = 0; q < 3; ++q)                             \
      GLDS16(src + q * 512, dst + q * 512);                                   \
  }

__global__ __launch_bounds__(512, 2) void deform_kernel(
    const __bf16* __restrict__ xT, const float* __restrict__ offm,
    const __bf16* __restrict__ wBTp, const float* __restrict__ bias,
    float* __restrict__ out) {
  __shared__ alignas(16) __bf16 Blds[BSTG];    // 24576 B
  __shared__ __bf16 offt[27][128];             // 6912 B

  int t = threadIdx.x;
  int lane = t & 63;
  int wv = __builtin_amdgcn_readfirstlane(t >> 6);   // 0..7
  int ln15 = lane & 15;

  // XCD-chunked bijective swizzle (nwg=2048 % 8 == 0)
  int bid = (int)blockIdx.x;
  int nb = (bid & 7) * 256 + (bid >> 3);
  int b = nb >> 7;                 // batch
  int h = nb & 127;                // row; block covers the full 128-wide row

  int pl = (wv << 4) + ln15;       // pixel 0..127 this lane computes
  int wg = pl;                     // global w coordinate (w0 = 0)
  unsigned choff = (unsigned)((lane >> 4) << 4);

  const __bf16* xb = xT + (size_t)b * HW * CIN;
  const float* ob = offm + (size_t)b * 27 * HW;

  unsigned long long ba = (unsigned long long)(const void*)xb;
  u32x4 rsrcX;
  rsrcX.x = (unsigned)ba; rsrcX.y = (unsigned)(ba >> 32);
  rsrcX.z = 0xffffffffu;  rsrcX.w = 0x00020000u;

  for (int e = t; e < 27 * 128; e += 512) {
    int o = e >> 7, p = e & 127;
    offt[o][p] = (__bf16)ob[(size_t)o * HW + (size_t)h * W + p];
  }
  __syncthreads();

  f32x4 acc[6];
#pragma unroll
  for (int nt = 0; nt < 6; ++nt) acc[nt] = (f32x4){0.f, 0.f, 0.f, 0.f};

  u32x4 g[12];
  f32x4 wd;
  const __bf16* bfrag = Blds + (size_t)ln15 * BPITCH + ((lane >> 4) << 3);

  // prologue: establish steady-state queue [G(0) x12, DMA(0) x3]
  GISS(0, g, wd);
  STAGE_B(0);

  for (int k = 0; k < 9; ++k) {
    // G(k) complete at vmcnt(3); own DMA(k) may still be in flight
    asm volatile("s_waitcnt vmcnt(3)" ::: "memory");
    __builtin_amdgcn_sched_barrier(0);          // rule #18

    bf16x8 af0, af1, af2;
    COMBINE_KS(g, 0, wd, af0);
    COMBINE_KS(g, 1, wd, af1);
    COMBINE_KS(g, 2, wd, af2);

    __syncthreads();   // drains own DMA(k); barrier => Blds[k] valid

    if (k < 8) { GISS(k + 1, g, wd); }   // fly across MFMA + sync2

#pragma unroll
    for (int nt = 0; nt < 6; ++nt) {
      const __bf16* bp = bfrag + nt * 16 * BPITCH;
      bf16x8 b0 = *(const bf16x8*)(bp);
      bf16x8 b1 = *(const bf16x8*)(bp + 32);
      bf16x8 b2 = *(const bf16x8*)(bp + 64);
      acc[nt] = __builtin_amdgcn_mfma_f32_16x16x32_bf16(af0, b0, acc[nt], 0, 0, 0);
      acc[nt] = __builtin_amdgcn_mfma_f32_16x16x32_bf16(af1, b1, acc[nt], 0, 0, 0);
      acc[nt] = __builtin_amdgcn_mfma_f32_16x16x32_bf16(af2, b2, acc[nt], 0, 0, 0);
    }

    if (k < 8) {
      __syncthreads();   // readers done (drains G(k+1), overlapped w/ MFMA)
      STAGE_B(k + 1);    // DMA into Blds, post-barrier
    }
  }

  float* outb = out + (size_t)b * COUT * HW + (size_t)h * W;
  int prow = (wv << 4) + ((lane >> 4) << 2);
#pragma unroll
  for (int nt = 0; nt < 6; ++nt) {
    int ch = nt * 16 + ln15;
    float bv = bias[ch];
    float4 o4;
    o4.x = acc[nt][0] + bv;
    o4.y = acc[nt][1] + bv;
    o4.z = acc[nt][2] + bv;
    o4.w = acc[nt][3] + bv;
    *(float4*)(outb + (size_t)ch * HW + prow) = o4;
  }
}

// ---------------------------------------------------------------------------
extern "C" void kernel_launch(void* const* d_in, const int* in_sizes, int n_in,
                              void* d_out, int out_size, void* d_ws, size_t ws_size,
                              hipStream_t stream) {
  const float* x        = (const float*)d_in[0];
  const float* weight   = (const float*)d_in[1];
  const float* bias     = (const float*)d_in[2];
  const float* offset_w = (const float*)d_in[3];
  const float* offset_b = (const float*)d_in[4];
  const float* mask_w   = (const float*)d_in[5];
  const float* mask_b   = (const float*)d_in[6];
  float* out = (float*)d_out;

  __bf16* xT   = (__bf16*)d_ws;                              // NPIX*96 bf16
  float*  offm = (float*)(xT + (size_t)NPIX * CIN);          // 16*27*16384 f32
  __bf16* wOT  = (__bf16*)(offm + (size_t)BATCH * 27 * HW);  // 27648 bf16
  __bf16* wBTp = wOT + NOT;                                  // 9*9984 + 2560 bf16

  const int nPrep = NOT + 9 * BTAP + 2560;
  prep_weights<<<(nPrep + 255) / 256, 256, 0, stream>>>(weight, offset_w, mask_w, wOT, wBTp);
  nhwc_kernel<<<NPIX / 256, 256, 0, stream>>>(x, xT);
  offmask_mfma<<<BATCH * H * (W / 64), 256, 0, stream>>>(xT, wOT, offset_b, mask_b, offm);
  deform_kernel<<<BATCH * H, 512, 0, stream>>>(xT, offm, wBTp, bias, out);
}

// Round 17
// 260.495 us; speedup vs baseline: 1.0946x; 1.0946x over previous
//
#include <hip/hip_runtime.h>
#include <math.h>

#define W 128
#define H 128
#define HW 16384
#define CIN 96
#define COUT 96
#define BATCH 16
#define NPIX (BATCH * HW)
#define BPITCH 104                 // padded B row pitch (bf16): 2-way banks max
#define BTAP (COUT * BPITCH)       // 9984 elems per tap image
#define BSTG 10240                 // LDS B buffer elems (20480 B)
#define NOT (27 * 32 * 32)         // wOT elems

typedef __bf16 bf16x8 __attribute__((ext_vector_type(8)));
typedef float f32x4 __attribute__((ext_vector_type(4)));
typedef unsigned int u32x4 __attribute__((ext_vector_type(4)));

typedef const unsigned int __attribute__((address_space(1))) gu32;
typedef unsigned int __attribute__((address_space(3))) lu32;
#define GLDS16(g, l) __builtin_amdgcn_global_load_lds((gu32*)(g), (lu32*)(l), 16, 0, 0)

__device__ inline float bflo(unsigned d) { union { unsigned u; float f; } t; t.u = d << 16; return t.f; }
__device__ inline float bfhi(unsigned d) { union { unsigned u; float f; } t; t.u = d & 0xffff0000u; return t.f; }

// ---------------------------------------------------------------------------
// Weight prep (R10-validated): wOT (offset/mask MFMA tiles), wBTp (padded
// deform weights for LDS DMA).
// ---------------------------------------------------------------------------
__global__ void prep_weights(const float* __restrict__ weight,
                             const float* __restrict__ offset_w,
                             const float* __restrict__ mask_w,
                             __bf16* __restrict__ wOT,
                             __bf16* __restrict__ wBTp) {
  int idx = blockIdx.x * blockDim.x + threadIdx.x;
  if (idx < NOT) {
    int c = idx & 31;
    int o = (idx >> 5) & 31;
    int ks = idx >> 10;
    int tap = ks / 3;
    int cg = (ks % 3) * 32 + c;
    float v = 0.f;
    if (o < 18)      v = offset_w[(o * CIN + cg) * 9 + tap];
    else if (o < 27) v = mask_w[((o - 18) * CIN + cg) * 9 + tap];
    wOT[idx] = (__bf16)v;
  } else {
    int j = idx - NOT;
    if (j < 9 * BTAP + 256) {
      int c = j % BPITCH;
      int o = (j / BPITCH) % COUT;
      int tap = j / BTAP;
      float v = 0.f;
      if (tap < 9 && c < CIN) v = weight[(o * CIN + c) * 9 + tap];
      wBTp[j] = (__bf16)v;
    }
  }
}

// ---------------------------------------------------------------------------
// NHWC relayout (validated).
// ---------------------------------------------------------------------------
__global__ __launch_bounds__(256) void nhwc_kernel(const float* __restrict__ x,
                                                   __bf16* __restrict__ xT) {
  int tid = blockIdx.x * 256 + threadIdx.x;
  int b = tid >> 14, pix = tid & (HW - 1);
  const float* xp = x + (size_t)b * CIN * HW + pix;
  __bf16* op = xT + (size_t)tid * CIN;
#pragma unroll
  for (int c0 = 0; c0 < CIN; c0 += 8) {
    bf16x8 v;
#pragma unroll
    for (int j = 0; j < 8; ++j) v[j] = (__bf16)xp[(size_t)(c0 + j) * HW];
    *(bf16x8*)(op + c0) = v;
  }
}

// ---------------------------------------------------------------------------
// FUSED kernel: phase A = offmask MFMA GEMM (R10-validated tap loop) writing
// bias+sigmoid'd results DIRECTLY into the offt LDS tile (no offm global
// round-trip); fusion barrier; phase B = deform conv (R15-validated loop,
// invariant re-established after the barrier).
// ---------------------------------------------------------------------------
#define OISS_TAP(TAP, G) {                                                    \
    int ki = (TAP) / 3, kj = (TAP) % 3;                                       \
    int yy = h + ki - 1, xx = wg + kj - 1;                                    \
    bool ok = ((unsigned)yy < (unsigned)H) && ((unsigned)xx < (unsigned)W);   \
    unsigned vo = ok ? (unsigned)((yy * W + xx) * 192) + choff : 0x7f000000u; \
    asm volatile("buffer_load_dwordx4 %0, %1, %2, %3 offen"                   \
                 : "=v"(G[0]) : "v"(vo), "s"(rsrcX), "s"(0));                 \
    asm volatile("buffer_load_dwordx4 %0, %1, %2, %3 offen"                   \
                 : "=v"(G[1]) : "v"(vo), "s"(rsrcX), "s"(64));                \
    asm volatile("buffer_load_dwordx4 %0, %1, %2, %3 offen"                   \
                 : "=v"(G[2]) : "v"(vo), "s"(rsrcX), "s"(128));               \
  }

#define OISS_B(TAP)                                                           \
  _Pragma("unroll") for (int s = 0; s < 3; ++s)                               \
  _Pragma("unroll") for (int nt = 0; nt < 2; ++nt)                            \
    asm volatile("buffer_load_dwordx4 %0, %1, %2, %3 offen"                   \
                 : "=v"(bb[s * 2 + nt])                                       \
                 : "v"(voffB), "s"(rsrcW),                                    \
                   "s"((TAP) * 6144 + s * 2048 + nt * 1024));

#define OCOMP(GC)                                                             \
  _Pragma("unroll") for (int s = 0; s < 3; ++s) {                             \
    bf16x8 a = __builtin_bit_cast(bf16x8, GC[s]);                             \
    oacc[0] = __builtin_amdgcn_mfma_f32_16x16x32_bf16(                        \
        a, __builtin_bit_cast(bf16x8, bb[s * 2 + 0]), oacc[0], 0, 0, 0);      \
    oacc[1] = __builtin_amdgcn_mfma_f32_16x16x32_bf16(                        \
        a, __builtin_bit_cast(bf16x8, bb[s * 2 + 1]), oacc[1], 0, 0, 0);      \
  }

#define GISS(K, G, WD) {                                                      \
    float dyv = (float)offt[2 * (K)][pl];                                     \
    float dxv = (float)offt[2 * (K) + 1][pl];                                 \
    float mv  = (float)offt[18 + (K)][pl];                                    \
    int ki = (K) / 3, kj = (K) % 3;                                           \
    float py = (float)(h - 1 + ki) + dyv;                                     \
    float px = (float)(wg - 1 + kj) + dxv;                                    \
    float fy = floorf(py), fx = floorf(px);                                   \
    float wyf = py - fy, wxf = px - fx;                                       \
    int iy0 = (int)fy, ix0 = (int)fx;                                         \
    int iy1 = iy0 + 1, ix1 = ix0 + 1;                                         \
    bool y0ok = (unsigned)iy0 < (unsigned)H;                                  \
    bool y1ok = (unsigned)iy1 < (unsigned)H;                                  \
    bool x0ok = (unsigned)ix0 < (unsigned)W;                                  \
    bool x1ok = (unsigned)ix1 < (unsigned)W;                                  \
    WD[0] = (y0ok && x0ok) ? (1.f - wyf) * (1.f - wxf) * mv : 0.f;            \
    WD[1] = (y0ok && x1ok) ? (1.f - wyf) * wxf * mv : 0.f;                    \
    WD[2] = (y1ok && x0ok) ? wyf * (1.f - wxf) * mv : 0.f;                    \
    WD[3] = (y1ok && x1ok) ? wyf * wxf * mv : 0.f;                            \
    int cy0 = min(max(iy0, 0), H - 1), cy1 = min(max(iy1, 0), H - 1);         \
    int cx0 = min(max(ix0, 0), W - 1), cx1 = min(max(ix1, 0), W - 1);         \
    unsigned v00 = (unsigned)((cy0 * W + cx0) * 192) + choff;                 \
    unsigned v01 = (unsigned)((cy0 * W + cx1) * 192) + choff;                 \
    unsigned v10 = (unsigned)((cy1 * W + cx0) * 192) + choff;                 \
    unsigned v11 = (unsigned)((cy1 * W + cx1) * 192) + choff;                 \
    _Pragma("unroll") for (int ks = 0; ks < 3; ++ks) {                        \
      asm volatile("buffer_load_dwordx4 %0, %1, %2, %3 offen"                 \
                   : "=v"(G[ks * 4 + 0]) : "v"(v00), "s"(rsrcX), "s"(ks * 64)); \
      asm volatile("buffer_load_dwordx4 %0, %1, %2, %3 offen"                 \
                   : "=v"(G[ks * 4 + 1]) : "v"(v01), "s"(rsrcX), "s"(ks * 64)); \
      asm volatile("buffer_load_dwordx4 %0, %1, %2, %3 offen"                 \
                   : "=v"(G[ks * 4 + 2]) : "v"(v10), "s"(rsrcX), "s"(ks * 64)); \
      asm volatile("buffer_load_dwordx4 %0, %1, %2, %3 offen"                 \
                   : "=v"(G[ks * 4 + 3]) : "v"(v11), "s"(rsrcX), "s"(ks * 64)); \
    } }

#define COMBINE_KS(G, KS, WV, AF)                                             \
  _Pragma("unroll") for (int j = 0; j < 8; ++j) {                             \
    unsigned d00 = G[(KS) * 4 + 0][j >> 1], d01 = G[(KS) * 4 + 1][j >> 1];    \
    unsigned d10 = G[(KS) * 4 + 2][j >> 1], d11 = G[(KS) * 4 + 3][j >> 1];    \
    float v00 = (j & 1) ? bfhi(d00) : bflo(d00);                              \
    float v01 = (j & 1) ? bfhi(d01) : bflo(d01);                              \
    float v10 = (j & 1) ? bfhi(d10) : bflo(d10);                              \
    float v11 = (j & 1) ? bfhi(d11) : bflo(d11);                              \
    AF[j] = (__bf16)(WV[0] * v00 + WV[1] * v01 + WV[2] * v10 + WV[3] * v11);  \
  }

#define STAGE_B(K) {                                                          \
    const __bf16* src = wBTp + (size_t)(K) * BTAP + (size_t)wv * 2560 +       \
                        (size_t)lane * 8;                                     \
    __bf16* dst = Blds + wv * 2560;                                           \
    _Pragma("unroll") for (int q = 0; q < 5; ++q)                             \
      GLDS16(src + q * 512, dst + q * 512);                                   \
  }

__global__ __launch_bounds__(256, 2) void fused_kernel(
    const __bf16* __restrict__ xT, const __bf16* __restrict__ wOT,
    const __bf16* __restrict__ wBTp,
    const float* __restrict__ offset_b, const float* __restrict__ mask_b,
    const float* __restrict__ bias, float* __restrict__ out) {
  __shared__ alignas(16) __bf16 Blds[BSTG];    // 20480 B
  __shared__ __bf16 offt[27][64];              // 3456 B

  int t = threadIdx.x;
  int lane = t & 63;
  int wv = __builtin_amdgcn_readfirstlane(t >> 6);
  int ln15 = lane & 15;

  // XCD-chunked bijective swizzle (nwg=4096 % 8 == 0)
  int bid = (int)blockIdx.x;
  int nb = (bid & 7) * 512 + (bid >> 3);
  int b = nb >> 8;
  int rem = nb & 255;
  int h = rem >> 1;
  int w0 = (rem & 1) << 6;

  int pl = (wv << 4) + ln15;            // local pixel this lane computes
  int wg = w0 + pl;                     // its global w coordinate
  unsigned choff = (unsigned)((lane >> 4) << 4);

  const __bf16* xb = xT + (size_t)b * HW * CIN;

  // SRSRC for batch-b NHWC image: bounds-checked (serves phase A's OOB-tap
  // zero-fill; phase B's clamped addresses are always in-bounds)
  unsigned long long ba = (unsigned long long)(const void*)xb;
  u32x4 rsrcX;
  rsrcX.x = (unsigned)ba; rsrcX.y = (unsigned)(ba >> 32);
  rsrcX.z = (unsigned)(HW * 192);
  rsrcX.w = 0x00020000u;
  unsigned long long bwo = (unsigned long long)(const void*)wOT;
  u32x4 rsrcW;
  rsrcW.x = (unsigned)bwo; rsrcW.y = (unsigned)(bwo >> 32);
  rsrcW.z = (unsigned)(NOT * 2);
  rsrcW.w = 0x00020000u;
  unsigned voffB = (unsigned)(ln15 * 64 + ((lane >> 4) << 4));

  int prow_l = (wv << 4) + ((lane >> 4) << 2);   // local pixel base of D rows

  // ================= PHASE A: offset/mask conv (R10-proven) =================
  {
    f32x4 oacc[2];
    oacc[0] = (f32x4){0.f, 0.f, 0.f, 0.f};
    oacc[1] = (f32x4){0.f, 0.f, 0.f, 0.f};
    u32x4 gA[3], gB[3], bb[6];

    OISS_TAP(0, gA);
#pragma unroll
    for (int tap = 0; tap < 9; ++tap) {
      OISS_B(tap);
      if (tap < 8) {
        if (tap & 1) { OISS_TAP(tap + 1, gA); } else { OISS_TAP(tap + 1, gB); }
        asm volatile("s_waitcnt vmcnt(3)" ::: "memory");
      } else {
        asm volatile("s_waitcnt vmcnt(0)" ::: "memory");
      }
      __builtin_amdgcn_sched_barrier(0);
      if (tap & 1) { OCOMP(gB); } else { OCOMP(gA); }
    }

    // epilogue -> offt LDS (bias + sigmoid), D row = pixel, col = o
    {
      float bv = offset_b[ln15];
#pragma unroll
      for (int r = 0; r < 4; ++r)
        offt[ln15][prow_l + r] = (__bf16)(oacc[0][r] + bv);
    }
    if (ln15 < 11) {
      int o = 16 + ln15;
      bool sig = (o >= 18);
      float bv = sig ? mask_b[o - 18] : offset_b[o];
#pragma unroll
      for (int r = 0; r < 4; ++r) {
        float v = oacc[1][r] + bv;
        if (sig) v = 1.f / (1.f + expf(-v));
        offt[o][prow_l + r] = (__bf16)v;
      }
    }
  }
  __syncthreads();   // fusion barrier: offt visible to all waves

  // ================= PHASE B: deform conv (R15-proven) ======================
  f32x4 acc[6];
#pragma unroll
  for (int nt = 0; nt < 6; ++nt) acc[nt] = (f32x4){0.f, 0.f, 0.f, 0.f};

  u32x4 g[12];
  f32x4 wd;
  const __bf16* bfrag = Blds + (size_t)ln15 * BPITCH + ((lane >> 4) << 3);

  // prologue: establish steady-state queue [G(0) x12, DMA(0) x5]
  GISS(0, g, wd);
  STAGE_B(0);

  for (int k = 0; k < 9; ++k) {
    asm volatile("s_waitcnt vmcnt(5)" ::: "memory");
    __builtin_amdgcn_sched_barrier(0);          // rule #18

    bf16x8 af0, af1, af2;
    COMBINE_KS(g, 0, wd, af0);
    COMBINE_KS(g, 1, wd, af1);
    COMBINE_KS(g, 2, wd, af2);

    __syncthreads();   // drains own DMA(k); barrier => Blds[k] valid

    if (k < 8) { GISS(k + 1, g, wd); }   // fly across MFMA + sync2

#pragma unroll
    for (int nt = 0; nt < 6; ++nt) {
      const __bf16* bp = bfrag + nt * 16 * BPITCH;
      bf16x8 b0 = *(const bf16x8*)(bp);
      bf16x8 b1 = *(const bf16x8*)(bp + 32);
      bf16x8 b2 = *(const bf16x8*)(bp + 64);
      acc[nt] = __builtin_amdgcn_mfma_f32_16x16x32_bf16(af0, b0, acc[nt], 0, 0, 0);
      acc[nt] = __builtin_amdgcn_mfma_f32_16x16x32_bf16(af1, b1, acc[nt], 0, 0, 0);
      acc[nt] = __builtin_amdgcn_mfma_f32_16x16x32_bf16(af2, b2, acc[nt], 0, 0, 0);
    }

    if (k < 8) {
      __syncthreads();   // readers done (drains G(k+1), overlapped w/ MFMA)
      STAGE_B(k + 1);    // DMA into Blds, post-barrier
    }
  }

  float* outb = out + (size_t)b * COUT * HW + (size_t)h * W;
  int prow = w0 + prow_l;
#pragma unroll
  for (int nt = 0; nt < 6; ++nt) {
    int ch = nt * 16 + ln15;
    float bv = bias[ch];
    float4 o4;
    o4.x = acc[nt][0] + bv;
    o4.y = acc[nt][1] + bv;
    o4.z = acc[nt][2] + bv;
    o4.w = acc[nt][3] + bv;
    *(float4*)(outb + (size_t)ch * HW + prow) = o4;
  }
}

// ---------------------------------------------------------------------------
extern "C" void kernel_launch(void* const* d_in, const int* in_sizes, int n_in,
                              void* d_out, int out_size, void* d_ws, size_t ws_size,
                              hipStream_t stream) {
  const float* x        = (const float*)d_in[0];
  const float* weight   = (const float*)d_in[1];
  const float* bias     = (const float*)d_in[2];
  const float* offset_w = (const float*)d_in[3];
  const float* offset_b = (const float*)d_in[4];
  const float* mask_w   = (const float*)d_in[5];
  const float* mask_b   = (const float*)d_in[6];
  float* out = (float*)d_out;

  __bf16* xT   = (__bf16*)d_ws;                              // NPIX*96 bf16
  __bf16* wOT  = xT + (size_t)NPIX * CIN;                    // 27648 bf16
  __bf16* wBTp = wOT + NOT;                                  // 9*9984 + 256 bf16

  const int nPrep = NOT + 9 * BTAP + 256;
  prep_weights<<<(nPrep + 255) / 256, 256, 0, stream>>>(weight, offset_w, mask_w, wOT, wBTp);
  nhwc_kernel<<<NPIX / 256, 256, 0, stream>>>(x, xT);
  fused_kernel<<<BATCH * H * (W / 64), 256, 0, stream>>>(
      xT, wOT, wBTp, offset_b, mask_b, bias, out);
}

// Round 18
// 260.183 us; speedup vs baseline: 1.0959x; 1.0012x over previous
//
#include <hip/hip_runtime.h>
#include <math.h>

#define W 128
#define H 128
#define HW 16384
#define CIN 96
#define COUT 96
#define BATCH 16
#define NPIX (BATCH * HW)
#define BPITCH 104                 // padded B row pitch (bf16): 2-way banks max
#define BTAP (COUT * BPITCH)       // 9984 elems per tap image
#define BSTG 10240                 // LDS B buffer elems (20480 B)
#define NOT (27 * 32 * 32)         // wOT elems

typedef __bf16 bf16x8 __attribute__((ext_vector_type(8)));
typedef float f32x4 __attribute__((ext_vector_type(4)));
typedef unsigned int u32x4 __attribute__((ext_vector_type(4)));

typedef const unsigned int __attribute__((address_space(1))) gu32;
typedef unsigned int __attribute__((address_space(3))) lu32;
#define GLDS16(g, l) __builtin_amdgcn_global_load_lds((gu32*)(g), (lu32*)(l), 16, 0, 0)

__device__ inline float bflo(unsigned d) { union { unsigned u; float f; } t; t.u = d << 16; return t.f; }
__device__ inline float bfhi(unsigned d) { union { unsigned u; float f; } t; t.u = d & 0xffff0000u; return t.f; }

// ---------------------------------------------------------------------------
// Weight prep (R10-validated): wOT (offset/mask MFMA tiles), wBTp (padded
// deform weights for LDS DMA).
// ---------------------------------------------------------------------------
__global__ void prep_weights(const float* __restrict__ weight,
                             const float* __restrict__ offset_w,
                             const float* __restrict__ mask_w,
                             __bf16* __restrict__ wOT,
                             __bf16* __restrict__ wBTp) {
  int idx = blockIdx.x * blockDim.x + threadIdx.x;
  if (idx < NOT) {
    int c = idx & 31;
    int o = (idx >> 5) & 31;
    int ks = idx >> 10;
    int tap = ks / 3;
    int cg = (ks % 3) * 32 + c;
    float v = 0.f;
    if (o < 18)      v = offset_w[(o * CIN + cg) * 9 + tap];
    else if (o < 27) v = mask_w[((o - 18) * CIN + cg) * 9 + tap];
    wOT[idx] = (__bf16)v;
  } else {
    int j = idx - NOT;
    if (j < 9 * BTAP + 256) {
      int c = j % BPITCH;
      int o = (j / BPITCH) % COUT;
      int tap = j / BTAP;
      float v = 0.f;
      if (tap < 9 && c < CIN) v = weight[(o * CIN + c) * 9 + tap];
      wBTp[j] = (__bf16)v;
    }
  }
}

// ---------------------------------------------------------------------------
// NHWC relayout (validated).
// ---------------------------------------------------------------------------
__global__ __launch_bounds__(256) void nhwc_kernel(const float* __restrict__ x,
                                                   __bf16* __restrict__ xT) {
  int tid = blockIdx.x * 256 + threadIdx.x;
  int b = tid >> 14, pix = tid & (HW - 1);
  const float* xp = x + (size_t)b * CIN * HW + pix;
  __bf16* op = xT + (size_t)tid * CIN;
#pragma unroll
  for (int c0 = 0; c0 < CIN; c0 += 8) {
    bf16x8 v;
#pragma unroll
    for (int j = 0; j < 8; ++j) v[j] = (__bf16)xp[(size_t)(c0 + j) * HW];
    *(bf16x8*)(op + c0) = v;
  }
}

// ---------------------------------------------------------------------------
// FUSED kernel. Phase A: offmask MFMA GEMM, now DEPTH-2 pipelined (both
// A-tap and B-weight streams issued one full tap ahead; vmcnt(9) retires
// exactly the current tap's 9 loads, leaving next tap's 9 in flight with a
// full tap of latency cover -- removes the ~400cy/tap exposed B-load stall
// of the depth-1 version). Writes offsets/masks to offt LDS. Phase B:
// deform conv, R15/R17-proven, byte-identical.
// ---------------------------------------------------------------------------
#define OISS_TAP(TAP, G) {                                                    \
    int ki = (TAP) / 3, kj = (TAP) % 3;                                       \
    int yy = h + ki - 1, xx = wg + kj - 1;                                    \
    bool ok = ((unsigned)yy < (unsigned)H) && ((unsigned)xx < (unsigned)W);   \
    unsigned vo = ok ? (unsigned)((yy * W + xx) * 192) + choff : 0x7f000000u; \
    asm volatile("buffer_load_dwordx4 %0, %1, %2, %3 offen"                   \
                 : "=v"(G[0]) : "v"(vo), "s"(rsrcX), "s"(0));                 \
    asm volatile("buffer_load_dwordx4 %0, %1, %2, %3 offen"                   \
                 : "=v"(G[1]) : "v"(vo), "s"(rsrcX), "s"(64));                \
    asm volatile("buffer_load_dwordx4 %0, %1, %2, %3 offen"                   \
                 : "=v"(G[2]) : "v"(vo), "s"(rsrcX), "s"(128));               \
  }

#define OISS_B(TAP, BB)                                                       \
  _Pragma("unroll") for (int s = 0; s < 3; ++s)                               \
  _Pragma("unroll") for (int nt = 0; nt < 2; ++nt)                            \
    asm volatile("buffer_load_dwordx4 %0, %1, %2, %3 offen"                   \
                 : "=v"(BB[s * 2 + nt])                                       \
                 : "v"(voffB), "s"(rsrcW),                                    \
                   "s"((TAP) * 6144 + s * 2048 + nt * 1024));

#define OCOMP(GC, BB)                                                         \
  _Pragma("unroll") for (int s = 0; s < 3; ++s) {                             \
    bf16x8 a = __builtin_bit_cast(bf16x8, GC[s]);                             \
    oacc[0] = __builtin_amdgcn_mfma_f32_16x16x32_bf16(                        \
        a, __builtin_bit_cast(bf16x8, BB[s * 2 + 0]), oacc[0], 0, 0, 0);      \
    oacc[1] = __builtin_amdgcn_mfma_f32_16x16x32_bf16(                        \
        a, __builtin_bit_cast(bf16x8, BB[s * 2 + 1]), oacc[1], 0, 0, 0);      \
  }

#define GISS(K, G, WD) {                                                      \
    float dyv = (float)offt[2 * (K)][pl];                                     \
    float dxv = (float)offt[2 * (K) + 1][pl];                                 \
    float mv  = (float)offt[18 + (K)][pl];                                    \
    int ki = (K) / 3, kj = (K) % 3;                                           \
    float py = (float)(h - 1 + ki) + dyv;                                     \
    float px = (float)(wg - 1 + kj) + dxv;                                    \
    float fy = floorf(py), fx = floorf(px);                                   \
    float wyf = py - fy, wxf = px - fx;                                       \
    int iy0 = (int)fy, ix0 = (int)fx;                                         \
    int iy1 = iy0 + 1, ix1 = ix0 + 1;                                         \
    bool y0ok = (unsigned)iy0 < (unsigned)H;                                  \
    bool y1ok = (unsigned)iy1 < (unsigned)H;                                  \
    bool x0ok = (unsigned)ix0 < (unsigned)W;                                  \
    bool x1ok = (unsigned)ix1 < (unsigned)W;                                  \
    WD[0] = (y0ok && x0ok) ? (1.f - wyf) * (1.f - wxf) * mv : 0.f;            \
    WD[1] = (y0ok && x1ok) ? (1.f - wyf) * wxf * mv : 0.f;                    \
    WD[2] = (y1ok && x0ok) ? wyf * (1.f - wxf) * mv : 0.f;                    \
    WD[3] = (y1ok && x1ok) ? wyf * wxf * mv : 0.f;                            \
    int cy0 = min(max(iy0, 0), H - 1), cy1 = min(max(iy1, 0), H - 1);         \
    int cx0 = min(max(ix0, 0), W - 1), cx1 = min(max(ix1, 0), W - 1);         \
    unsigned v00 = (unsigned)((cy0 * W + cx0) * 192) + choff;                 \
    unsigned v01 = (unsigned)((cy0 * W + cx1) * 192) + choff;                 \
    unsigned v10 = (unsigned)((cy1 * W + cx0) * 192) + choff;                 \
    unsigned v11 = (unsigned)((cy1 * W + cx1) * 192) + choff;                 \
    _Pragma("unroll") for (int ks = 0; ks < 3; ++ks) {                        \
      asm volatile("buffer_load_dwordx4 %0, %1, %2, %3 offen"                 \
                   : "=v"(G[ks * 4 + 0]) : "v"(v00), "s"(rsrcX), "s"(ks * 64)); \
      asm volatile("buffer_load_dwordx4 %0, %1, %2, %3 offen"                 \
                   : "=v"(G[ks * 4 + 1]) : "v"(v01), "s"(rsrcX), "s"(ks * 64)); \
      asm volatile("buffer_load_dwordx4 %0, %1, %2, %3 offen"                 \
                   : "=v"(G[ks * 4 + 2]) : "v"(v10), "s"(rsrcX), "s"(ks * 64)); \
      asm volatile("buffer_load_dwordx4 %0, %1, %2, %3 offen"                 \
                   : "=v"(G[ks * 4 + 3]) : "v"(v11), "s"(rsrcX), "s"(ks * 64)); \
    } }

#define COMBINE_KS(G, KS, WV, AF)                                             \
  _Pragma("unroll") for (int j = 0; j < 8; ++j) {                             \
    unsigned d00 = G[(KS) * 4 + 0][j >> 1], d01 = G[(KS) * 4 + 1][j >> 1];    \
    unsigned d10 = G[(KS) * 4 + 2][j >> 1], d11 = G[(KS) * 4 + 3][j >> 1];    \
    float v00 = (j & 1) ? bfhi(d00) : bflo(d00);                              \
    float v01 = (j & 1) ? bfhi(d01) : bflo(d01);                              \
    float v10 = (j & 1) ? bfhi(d10) : bflo(d10);                              \
    float v11 = (j & 1) ? bfhi(d11) : bflo(d11);                              \
    AF[j] = (__bf16)(WV[0] * v00 + WV[1] * v01 + WV[2] * v10 + WV[3] * v11);  \
  }

#define STAGE_B(K) {                                                          \
    const __bf16* src = wBTp + (size_t)(K) * BTAP + (size_t)wv * 2560 +       \
                        (size_t)lane * 8;                                     \
    __bf16* dst = Blds + wv * 2560;                                           \
    _Pragma("unroll") for (int q = 0; q < 5; ++q)                             \
      GLDS16(src + q * 512, dst + q * 512);                                   \
  }

__global__ __launch_bounds__(256, 2) void fused_kernel(
    const __bf16* __restrict__ xT, const __bf16* __restrict__ wOT,
    const __bf16* __restrict__ wBTp,
    const float* __restrict__ offset_b, const float* __restrict__ mask_b,
    const float* __restrict__ bias, float* __restrict__ out) {
  __shared__ alignas(16) __bf16 Blds[BSTG];    // 20480 B
  __shared__ __bf16 offt[27][64];              // 3456 B

  int t = threadIdx.x;
  int lane = t & 63;
  int wv = __builtin_amdgcn_readfirstlane(t >> 6);
  int ln15 = lane & 15;

  // XCD-chunked bijective swizzle (nwg=4096 % 8 == 0)
  int bid = (int)blockIdx.x;
  int nb = (bid & 7) * 512 + (bid >> 3);
  int b = nb >> 8;
  int rem = nb & 255;
  int h = rem >> 1;
  int w0 = (rem & 1) << 6;

  int pl = (wv << 4) + ln15;            // local pixel this lane computes
  int wg = w0 + pl;                     // its global w coordinate
  unsigned choff = (unsigned)((lane >> 4) << 4);

  const __bf16* xb = xT + (size_t)b * HW * CIN;

  // SRSRC for batch-b NHWC image: bounds-checked (phase A OOB-tap zero-fill)
  unsigned long long ba = (unsigned long long)(const void*)xb;
  u32x4 rsrcX;
  rsrcX.x = (unsigned)ba; rsrcX.y = (unsigned)(ba >> 32);
  rsrcX.z = (unsigned)(HW * 192);
  rsrcX.w = 0x00020000u;
  unsigned long long bwo = (unsigned long long)(const void*)wOT;
  u32x4 rsrcW;
  rsrcW.x = (unsigned)bwo; rsrcW.y = (unsigned)(bwo >> 32);
  rsrcW.z = (unsigned)(NOT * 2);
  rsrcW.w = 0x00020000u;
  unsigned voffB = (unsigned)(ln15 * 64 + ((lane >> 4) << 4));

  int prow_l = (wv << 4) + ((lane >> 4) << 2);   // local pixel base of D rows

  // ============ PHASE A: offset/mask conv, DEPTH-2 pipeline ============
  // Steady state at tap-k wait point: queue = [A(k):3, B(k):6, A(k+1):3,
  // B(k+1):6] = 18; vmcnt(9) retires A(k)+B(k); next tap's 9 keep flying
  // with a full tap (~OCOMP+issue) of cover. Banks alternate (even: gA/bb0,
  // odd: gB/bb1); re-issue into a bank only after its OCOMP consumed it.
  {
    f32x4 oacc[2];
    oacc[0] = (f32x4){0.f, 0.f, 0.f, 0.f};
    oacc[1] = (f32x4){0.f, 0.f, 0.f, 0.f};
    u32x4 gA[3], gB[3], bb0[6], bb1[6];

    OISS_TAP(0, gA);
    OISS_B(0, bb0);
#pragma unroll
    for (int tap = 0; tap < 9; ++tap) {
      if (tap < 8) {
        if (tap & 1) { OISS_TAP(tap + 1, gA); OISS_B(tap + 1, bb0); }
        else         { OISS_TAP(tap + 1, gB); OISS_B(tap + 1, bb1); }
        asm volatile("s_waitcnt vmcnt(9)" ::: "memory");
      } else {
        asm volatile("s_waitcnt vmcnt(0)" ::: "memory");
      }
      __builtin_amdgcn_sched_barrier(0);   // rule #18
      if (tap & 1) { OCOMP(gB, bb1); } else { OCOMP(gA, bb0); }
    }

    // epilogue -> offt LDS (bias + sigmoid), D row = pixel, col = o
    {
      float bv = offset_b[ln15];
#pragma unroll
      for (int r = 0; r < 4; ++r)
        offt[ln15][prow_l + r] = (__bf16)(oacc[0][r] + bv);
    }
    if (ln15 < 11) {
      int o = 16 + ln15;
      bool sig = (o >= 18);
      float bv = sig ? mask_b[o - 18] : offset_b[o];
#pragma unroll
      for (int r = 0; r < 4; ++r) {
        float v = oacc[1][r] + bv;
        if (sig) v = 1.f / (1.f + expf(-v));
        offt[o][prow_l + r] = (__bf16)v;
      }
    }
  }
  __syncthreads();   // fusion barrier: offt visible to all waves

  // ============ PHASE B: deform conv (R15/R17-proven, unchanged) ============
  f32x4 acc[6];
#pragma unroll
  for (int nt = 0; nt < 6; ++nt) acc[nt] = (f32x4){0.f, 0.f, 0.f, 0.f};

  u32x4 g[12];
  f32x4 wd;
  const __bf16* bfrag = Blds + (size_t)ln15 * BPITCH + ((lane >> 4) << 3);

  // prologue: establish steady-state queue [G(0) x12, DMA(0) x5]
  GISS(0, g, wd);
  STAGE_B(0);

  for (int k = 0; k < 9; ++k) {
    asm volatile("s_waitcnt vmcnt(5)" ::: "memory");
    __builtin_amdgcn_sched_barrier(0);          // rule #18

    bf16x8 af0, af1, af2;
    COMBINE_KS(g, 0, wd, af0);
    COMBINE_KS(g, 1, wd, af1);
    COMBINE_KS(g, 2, wd, af2);

    __syncthreads();   // drains own DMA(k); barrier => Blds[k] valid

    if (k < 8) { GISS(k + 1, g, wd); }   // fly across MFMA + sync2

#pragma unroll
    for (int nt = 0; nt < 6; ++nt) {
      const __bf16* bp = bfrag + nt * 16 * BPITCH;
      bf16x8 b0 = *(const bf16x8*)(bp);
      bf16x8 b1 = *(const bf16x8*)(bp + 32);
      bf16x8 b2 = *(const bf16x8*)(bp + 64);
      acc[nt] = __builtin_amdgcn_mfma_f32_16x16x32_bf16(af0, b0, acc[nt], 0, 0, 0);
      acc[nt] = __builtin_amdgcn_mfma_f32_16x16x32_bf16(af1, b1, acc[nt], 0, 0, 0);
      acc[nt] = __builtin_amdgcn_mfma_f32_16x16x32_bf16(af2, b2, acc[nt], 0, 0, 0);
    }

    if (k < 8) {
      __syncthreads();   // readers done (drains G(k+1), overlapped w/ MFMA)
      STAGE_B(k + 1);    // DMA into Blds, post-barrier
    }
  }

  float* outb = out + (size_t)b * COUT * HW + (size_t)h * W;
  int prow = w0 + prow_l;
#pragma unroll
  for (int nt = 0; nt < 6; ++nt) {
    int ch = nt * 16 + ln15;
    float bv = bias[ch];
    float4 o4;
    o4.x = acc[nt][0] + bv;
    o4.y = acc[nt][1] + bv;
    o4.z = acc[nt][2] + bv;
    o4.w = acc[nt][3] + bv;
    *(float4*)(outb + (size_t)ch * HW + prow) = o4;
  }
}

// ---------------------------------------------------------------------------
extern "C" void kernel_launch(void* const* d_in, const int* in_sizes, int n_in,
                              void* d_out, int out_size, void* d_ws, size_t ws_size,
                              hipStream_t stream) {
  const float* x        = (const float*)d_in[0];
  const float* weight   = (const float*)d_in[1];
  const float* bias     = (const float*)d_in[2];
  const float* offset_w = (const float*)d_in[3];
  const float* offset_b = (const float*)d_in[4];
  const float* mask_w   = (const float*)d_in[5];
  const float* mask_b   = (const float*)d_in[6];
  float* out = (float*)d_out;

  __bf16* xT   = (__bf16*)d_ws;                              // NPIX*96 bf16
  __bf16* wOT  = xT + (size_t)NPIX * CIN;                    // 27648 bf16
  __bf16* wBTp = wOT + NOT;                                  // 9*9984 + 256 bf16

  const int nPrep = NOT + 9 * BTAP + 256;
  prep_weights<<<(nPrep + 255) / 256, 256, 0, stream>>>(weight, offset_w, mask_w, wOT, wBTp);
  nhwc_kernel<<<NPIX / 256, 256, 0, stream>>>(x, xT);
  fused_kernel<<<BATCH * H * (W / 64), 256, 0, stream>>>(
      xT, wOT, wBTp, offset_b, mask_b, bias, out);
}